// Round 2
// baseline (379.411 us; speedup 1.0000x reference)
//
#include <hip/hip_runtime.h>
#include <hip/hip_bf16.h>

// Conv2D 3x3 s1 p1: x[8,16,512,512] f32, w[16,144] f32 -> out[8,16,512,512] f32
//
// Implicit GEMM on bf16 MFMA (16x16x32):
//   out[co][pixel] = sum_k W[co][k] * X[k][pixel],  k = tap*16 + ci, tap = kh*3+kw
//   K = 144 padded to 160 (5 MFMA steps of K=32); A (weights) zeroed for k>=144.
//   B fragment (k = quad*8+j) = 8 contiguous channels of one pixel -> one ds_read_b128
//   from channels-last bf16 LDS tile [18 rows][66 cols][16 ci].
//   16B-half swizzle (half ^ ((pixel>>2)&1)) -> 2-way (free) LDS conflicts both ways.
//
// Block: 256 thr (4 waves), out tile 16h x 64w, all 16 co. Wave owns 4 h-rows.
// Roofline: HBM 268 MB + halo ~ 290 MB -> ~46 us; MFMA ~3 us; LDS ~4 us.

#define IH 512
#define IW 512
#define CI 16
#define CO 16
#define TH 16
#define TW 64
#define LROWS (TH + 2)   // 18
#define LCOLS (TW + 2)   // 66

typedef short short8  __attribute__((ext_vector_type(8)));
typedef short short4v __attribute__((ext_vector_type(4)));
typedef float f32x4   __attribute__((ext_vector_type(4)));

__device__ __forceinline__ short f32_to_bf16_bits(float v) {
    __hip_bfloat16 b = __float2bfloat16(v);   // RNE
    return __builtin_bit_cast(short, b);
}

__global__ __launch_bounds__(256, 4)
void conv3x3_mfma(const float* __restrict__ x, const float* __restrict__ wgt,
                  float* __restrict__ out) {
    __shared__ short lds[LROWS * LCOLS * CI];  // bf16, channels-last, half-swizzled

    const int tid  = threadIdx.x;
    const int wave = tid >> 6;
    const int lane = tid & 63;
    const int quad = lane >> 4;
    const int l15  = lane & 15;

    const int wbase = blockIdx.x * TW;
    const int hbase = blockIdx.y * TH;
    const int n     = blockIdx.z;

    // ---- A fragments: W[co=l15][k], k = f*32 + quad*8 + j; zero for k>=144 ----
    short8 afrag[5];
#pragma unroll
    for (int f = 0; f < 5; ++f) {
#pragma unroll
        for (int j = 0; j < 8; ++j) {
            const int k = f * 32 + quad * 8 + j;
            float val = 0.0f;
            if (k < 144) {                       // uniform for f<4; predicated for f==4
                const int ci  = k & 15;
                const int tap = k >> 4;
                val = wgt[l15 * 144 + ci * 9 + tap];
            }
            afrag[f][j] = f32_to_bf16_bits(val);
        }
    }

    // ---- stage input tile (halo + zero-pad) as channels-last bf16 ----
    const float* xn = x + (size_t)n * CI * IH * IW;
    for (int cg = 0; cg < CI; cg += 4) {
        for (int row = wave; row < LROWS; row += 4) {
            const int gh  = hbase - 1 + row;
            const bool okh = (unsigned)gh < (unsigned)IH;
            for (int c = lane; c < LCOLS; c += 64) {
                const int gw = wbase - 1 + c;
                const bool ok = okh && ((unsigned)gw < (unsigned)IW);
                short4v pk;
#pragma unroll
                for (int j = 0; j < 4; ++j) {
                    const float v = ok ? xn[((size_t)(cg + j) * IH + gh) * IW + gw] : 0.0f;
                    pk[j] = f32_to_bf16_bits(v);
                }
                const int pixel = row * LCOLS + c;
                const int s2    = (pixel >> 1) & 2;          // 0 or 2
                const int slot  = (cg >> 2) ^ s2;            // 8B-group slot swizzle
                *(short4v*)&lds[pixel * 16 + slot * 4] = pk; // ds_write_b64
            }
        }
    }
    __syncthreads();

    // ---- per-f tap offsets (depend only on quad) ----
    const int q = quad & 1;          // which 8-channel half this lane consumes
    int doff[5];
#pragma unroll
    for (int f = 0; f < 5; ++f) {
        const int tap = (f < 4) ? (f * 2 + (quad >> 1)) : 8;
        const int kh  = tap / 3;     // const-divisor -> magic mul, hoisted
        const int kw  = tap - kh * 3;
        doff[f] = kh * LCOLS + kw;
    }

    // ---- MFMA main: 4 h-rows x 4 w-segments per wave, 5 K-steps each ----
    f32x4 acc[4][4];
#pragma unroll
    for (int r = 0; r < 4; ++r)
#pragma unroll
        for (int c4 = 0; c4 < 4; ++c4)
            acc[r][c4] = (f32x4){0.f, 0.f, 0.f, 0.f};

#pragma unroll
    for (int r = 0; r < 4; ++r) {
        const int hl = wave * 4 + r;
#pragma unroll
        for (int c4 = 0; c4 < 4; ++c4) {
            const int wl   = c4 * 16 + l15;
            const int pbase = hl * LCOLS + wl;   // LDS origin is (-1,-1): +kh,+kw only
#pragma unroll
            for (int f = 0; f < 5; ++f) {
                const int pixel = pbase + doff[f];
                const int half  = q ^ ((pixel >> 2) & 1);
                const short8 b  = *(const short8*)&lds[pixel * 16 + half * 8]; // ds_read_b128
                acc[r][c4] = __builtin_amdgcn_mfma_f32_16x16x32_bf16(afrag[f], b, acc[r][c4], 0, 0, 0);
            }
        }
    }

    // ---- store: C/D col = l15 = pixel, row = quad*4+reg = co ----
    float* on = out + (size_t)n * CO * IH * IW;
#pragma unroll
    for (int r = 0; r < 4; ++r) {
        const int gh = hbase + wave * 4 + r;
#pragma unroll
        for (int c4 = 0; c4 < 4; ++c4) {
            const int gw = wbase + c4 * 16 + l15;
#pragma unroll
            for (int reg = 0; reg < 4; ++reg) {
                const int co = quad * 4 + reg;
                on[((size_t)co * IH + gh) * IW + gw] = acc[r][c4][reg];
            }
        }
    }
}

extern "C" void kernel_launch(void* const* d_in, const int* in_sizes, int n_in,
                              void* d_out, int out_size, void* d_ws, size_t ws_size,
                              hipStream_t stream) {
    const float* x = (const float*)d_in[0];
    const float* w = (const float*)d_in[1];
    float* out     = (float*)d_out;

    dim3 grid(IW / TW, IH / TH, 8);   // 8 x 32 x 8 = 2048 blocks
    dim3 block(256);
    conv3x3_mfma<<<grid, block, 0, stream>>>(x, w, out);
}

// Round 3
// 274.924 us; speedup vs baseline: 1.3801x; 1.3801x over previous
//
#include <hip/hip_runtime.h>
#include <hip/hip_bf16.h>

// Conv2D 3x3 s1 p1: x[8,16,512,512] f32, w[16,144] f32 -> out[8,16,512,512] f32
//
// Implicit GEMM on bf16 MFMA (16x16x32), k = tap*16 + ci (K=144 pad 160).
// LDS tile: channels-last bf16 [18][66][16], 8B-slot swizzle slot=cg4^((pixel>>1)&2)
//   -> ds_read_b128 gives 8 contiguous channels (half = q ^ ((pixel>>2)&1)).
// R3 change: staging via global_load_dwordx4 (4 ch x 4 w per item) + in-register
//   4x4 transpose + 4x ds_write_b64 in wseg-rotated order (pixel-phase spread ->
//   ~2-way banks). Replaces R2's 160 scalar gather loads (latency-bound, 227us).

#define IH 512
#define IW 512
#define CI 16
#define CO 16
#define TH 16
#define TW 64
#define LROWS (TH + 2)   // 18
#define LCOLS (TW + 2)   // 66

typedef short short8  __attribute__((ext_vector_type(8)));
typedef short short4v __attribute__((ext_vector_type(4)));
typedef float f32x4   __attribute__((ext_vector_type(4)));

__device__ __forceinline__ short f32_to_bf16_bits(float v) {
    __hip_bfloat16 b = __float2bfloat16(v);   // RNE
    return __builtin_bit_cast(short, b);
}

__global__ __launch_bounds__(256, 4)
void conv3x3_mfma(const float* __restrict__ x, const float* __restrict__ wgt,
                  float* __restrict__ out) {
    __shared__ short lds[LROWS * LCOLS * CI];

    const int tid  = threadIdx.x;
    const int wave = tid >> 6;
    const int lane = tid & 63;
    const int quad = lane >> 4;
    const int l15  = lane & 15;

    const int wbase = blockIdx.x * TW;
    const int hbase = blockIdx.y * TH;
    const int n     = blockIdx.z;

    // ---- A fragments: W[co=l15][k], k = f*32 + quad*8 + j; zero for k>=144 ----
    short8 afrag[5];
#pragma unroll
    for (int f = 0; f < 5; ++f) {
#pragma unroll
        for (int j = 0; j < 8; ++j) {
            const int k = f * 32 + quad * 8 + j;
            float val = 0.0f;
            if (k < 144) {
                const int ci  = k & 15;
                const int tap = k >> 4;
                val = wgt[l15 * 144 + ci * 9 + tap];
            }
            afrag[f][j] = f32_to_bf16_bits(val);
        }
    }

    const float* xn = x + (size_t)n * CI * IH * IW;

    // ---- interior staging: 18 rows x 16 wsegs x 4 cgroups = 1152 items ----
    // item: 4x global_load_dwordx4 (ch cg4*4..+3, w gw..gw+3) -> transpose ->
    //       4x ds_write_b64, write order rotated by wseg (bank-phase spread)
#pragma unroll
    for (int it = 0; it < 5; ++it) {
        const int i = it * 256 + tid;
        if (it < 4 || i < 1152) {
            const int wseg = i & 15;
            const int cg4  = (i >> 4) & 3;
            const int row  = i >> 6;            // 0..17
            const int gh   = hbase - 1 + row;
            const int gw   = wbase + 4 * wseg;  // interior col c = 1+4*wseg
            short4v pk[4];
            if ((unsigned)gh < (unsigned)IH) {
                f32x4 v[4];
#pragma unroll
                for (int jj = 0; jj < 4; ++jj)
                    v[jj] = *(const f32x4*)(xn + ((size_t)(cg4 * 4 + jj) * IH + gh) * IW + gw);
#pragma unroll
                for (int j = 0; j < 4; ++j)
#pragma unroll
                    for (int jj = 0; jj < 4; ++jj)
                        pk[j][jj] = f32_to_bf16_bits(v[jj][j]);
            } else {
#pragma unroll
                for (int j = 0; j < 4; ++j) pk[j] = (short4v){0, 0, 0, 0};
            }
            const int pbase = row * LCOLS + 1 + 4 * wseg;
#pragma unroll
            for (int k = 0; k < 4; ++k) {
                const int j     = (k + wseg) & 3;       // rotate: spread pixel phase
                const int pixel = pbase + j;
                const int slot  = cg4 ^ ((pixel >> 1) & 2);
                *(short4v*)&lds[pixel * 16 + slot * 4] = pk[j];
            }
        }
    }

    // ---- halo cols c=0,65: 18 rows x 2 cols x 4 cgroups = 144 items ----
    if (tid < 144) {
        const int cg4  = tid & 3;
        const int col2 = (tid >> 2) & 1;
        const int row  = tid >> 3;              // 0..17
        const int c    = col2 ? (LCOLS - 1) : 0;
        const int gh   = hbase - 1 + row;
        const int gw   = wbase - 1 + c;
        const bool ok  = ((unsigned)gh < (unsigned)IH) && ((unsigned)gw < (unsigned)IW);
        short4v pk;
#pragma unroll
        for (int j = 0; j < 4; ++j) {
            const float v = ok ? xn[((size_t)(cg4 * 4 + j) * IH + gh) * IW + gw] : 0.0f;
            pk[j] = f32_to_bf16_bits(v);
        }
        const int pixel = row * LCOLS + c;
        const int slot  = cg4 ^ ((pixel >> 1) & 2);
        *(short4v*)&lds[pixel * 16 + slot * 4] = pk;
    }
    __syncthreads();

    // ---- per-f tap offsets (depend only on quad) ----
    const int q = quad & 1;
    int doff[5];
#pragma unroll
    for (int f = 0; f < 5; ++f) {
        const int tap = (f < 4) ? (f * 2 + (quad >> 1)) : 8;
        const int kh  = tap / 3;
        const int kw  = tap - kh * 3;
        doff[f] = kh * LCOLS + kw;
    }

    // ---- MFMA main: 4 h-rows x 4 w-segments per wave, 5 K-steps each ----
    f32x4 acc[4][4];
#pragma unroll
    for (int r = 0; r < 4; ++r)
#pragma unroll
        for (int c4 = 0; c4 < 4; ++c4)
            acc[r][c4] = (f32x4){0.f, 0.f, 0.f, 0.f};

#pragma unroll
    for (int r = 0; r < 4; ++r) {
        const int hl = wave * 4 + r;
#pragma unroll
        for (int c4 = 0; c4 < 4; ++c4) {
            const int wl    = c4 * 16 + l15;
            const int pbase = hl * LCOLS + wl;
#pragma unroll
            for (int f = 0; f < 5; ++f) {
                const int pixel = pbase + doff[f];
                const int half  = q ^ ((pixel >> 2) & 1);
                const short8 b  = *(const short8*)&lds[pixel * 16 + half * 8]; // ds_read_b128
                acc[r][c4] = __builtin_amdgcn_mfma_f32_16x16x32_bf16(afrag[f], b, acc[r][c4], 0, 0, 0);
            }
        }
    }

    // ---- store: C/D col = l15 = pixel, row = quad*4+reg = co ----
    float* on = out + (size_t)n * CO * IH * IW;
#pragma unroll
    for (int r = 0; r < 4; ++r) {
        const int gh = hbase + wave * 4 + r;
#pragma unroll
        for (int c4 = 0; c4 < 4; ++c4) {
            const int gw = wbase + c4 * 16 + l15;
#pragma unroll
            for (int reg = 0; reg < 4; ++reg) {
                const int co = quad * 4 + reg;
                on[((size_t)co * IH + gh) * IW + gw] = acc[r][c4][reg];
            }
        }
    }
}

extern "C" void kernel_launch(void* const* d_in, const int* in_sizes, int n_in,
                              void* d_out, int out_size, void* d_ws, size_t ws_size,
                              hipStream_t stream) {
    const float* x = (const float*)d_in[0];
    const float* w = (const float*)d_in[1];
    float* out     = (float*)d_out;

    dim3 grid(IW / TW, IH / TH, 8);   // 8 x 32 x 8 = 2048 blocks
    dim3 block(256);
    conv3x3_mfma<<<grid, block, 0, stream>>>(x, w, out);
}